// Round 16
// baseline (580.738 us; speedup 1.0000x reference)
//
#include <hip/hip_runtime.h>
#include <hip/hip_bf16.h>

#define NN 100000
#define NE 50000
#define NT 2000
#define DD 128
#define NEDGE 1600000
#define HID 512
#define OUTD 128
#define K1 (3*DD)   // 384: X layout [news | ent_agg | top_agg]
#define NBKT 391    // ceil(100000/256) buckets of 256 nodes
#define ECAP 4608   // fixed bucket capacity: mean 4096 + 8 sigma
#define CFB 19000   // prep: conv_feats blocks
#define SCB 392     // prep: scatter blocks
#define CWB 1024    // prep: conv_w blocks

typedef __bf16 bf16x8 __attribute__((ext_vector_type(8)));
typedef __bf16 bf16x4 __attribute__((ext_vector_type(4)));
typedef float  f32x4  __attribute__((ext_vector_type(4)));

__device__ __forceinline__ __bf16 f2b(float f) {
    __hip_bfloat16 h = __float2bfloat16(f);
    union { __hip_bfloat16 h; __bf16 b; } u; u.h = h; return u.b;
}

__device__ __forceinline__ void gll16(const void* g, void* l) {
    __builtin_amdgcn_global_load_lds((const __attribute__((address_space(1))) void*)g,
                                     (__attribute__((address_space(3))) void*)l, 16, 0, 0);
}

__device__ __forceinline__ float ftanh(float x) {
    x = fminf(fmaxf(x, -15.f), 15.f);
    float t = __expf(2.f * x);
    return (t - 1.f) / (t + 1.f);
}

// ======== prep: conv_feats | scatter_bucket | conv_w fused by blockIdx range ========
__global__ __launch_bounds__(256) void prep(const float* __restrict__ entf,
                                            const float* __restrict__ topf,
                                            const float* __restrict__ news,
                                            const int* __restrict__ er,
                                            const int* __restrict__ ec,
                                            const int* __restrict__ tr,
                                            const int* __restrict__ tc,
                                            const float* __restrict__ W1,
                                            const float* __restrict__ W2,
                                            __bf16* __restrict__ entb,
                                            __bf16* __restrict__ topb,
                                            __bf16* __restrict__ X,
                                            int* __restrict__ cnt_e,
                                            int* __restrict__ cnt_t,
                                            int* __restrict__ be,
                                            int* __restrict__ bt,
                                            __bf16* __restrict__ W1T,
                                            __bf16* __restrict__ W2T) {
    __shared__ int lhe[NBKT], lht[NBKT];   // scatter only
    __shared__ int lbe[NBKT], lbt[NBKT];
    const int bx = blockIdx.x;
    const int tid = threadIdx.x;

    if (bx < CFB) {
        // ---- conv_feats ----
        long i = ((long)bx * 256 + tid) * 4;
        const long NEL = (long)NE * DD;            // 6.4M
        const long NTL = (long)NT * DD;            // 0.256M
        if (i < NEL) {
            float4 v = *(const float4*)(entf + i);
            *(bf16x4*)(entb + i) = bf16x4{f2b(v.x), f2b(v.y), f2b(v.z), f2b(v.w)};
        } else if (i < NEL + NTL) {
            long j = i - NEL;
            float4 v = *(const float4*)(topf + j);
            *(bf16x4*)(topb + j) = bf16x4{f2b(v.x), f2b(v.y), f2b(v.z), f2b(v.w)};
        } else {
            long j = i - NEL - NTL;                // 0 .. 12.8M
            long row = j >> 7, col = j & 127;      // news [NN x 128]
            float4 v = *(const float4*)(news + j);
            *(bf16x4*)(X + row * K1 + col) = bf16x4{f2b(v.x), f2b(v.y), f2b(v.z), f2b(v.w)};
        }
    } else if (bx < CFB + SCB) {
        // ---- scatter_bucket ----
        const int sb = bx - CFB;
        for (int i = tid; i < NBKT; i += 256) { lhe[i] = 0; lht[i] = 0; }
        __syncthreads();
        const int base = sb * 4096;
        #pragma unroll 4
        for (int k = 0; k < 16; k++) {
            int e = base + k * 256 + tid;
            if (e < NEDGE) {
                atomicAdd(&lhe[er[e] >> 8], 1);
                atomicAdd(&lht[tr[e] >> 8], 1);
            }
        }
        __syncthreads();
        for (int i = tid; i < NBKT; i += 256) {
            int c = lhe[i];
            lbe[i] = c ? (i * ECAP + atomicAdd(&cnt_e[i], c)) : 0;
            lhe[i] = 0;
            c = lht[i];
            lbt[i] = c ? (i * ECAP + atomicAdd(&cnt_t[i], c)) : 0;
            lht[i] = 0;
        }
        __syncthreads();
        #pragma unroll 4
        for (int k = 0; k < 16; k++) {
            int e = base + k * 256 + tid;
            if (e < NEDGE) {
                int r = er[e];
                int b = r >> 8;
                int p = lbe[b] + atomicAdd(&lhe[b], 1);
                be[p] = ((r & 255) << 16) | ec[e];
                r = tr[e];
                b = r >> 8;
                p = lbt[b] + atomicAdd(&lht[b], 1);
                bt[p] = ((r & 255) << 16) | tc[e];
            }
        }
    } else {
        // ---- conv_w ----
        int i = (bx - CFB - SCB) * 256 + tid;
        if (i < K1 * HID) {
            int k = i / HID, n = i % HID;
            W1T[n * K1 + k] = f2b(W1[i]);
        } else {
            int j = i - K1 * HID;
            if (j < HID * OUTD) {
                int k = j / OUTD, n = j % OUTD;
                W2T[n * HID + k] = f2b(W2[j]);
            }
        }
    }
}

// ======== csr_agg: per-bucket CSR build in LDS + aggregate, fused ========
// Block = bucket (512 thr, 8 waves). Phase 1: hist+scan+reorder both edge
// streams into LDS lists (never touch global se/st). Phase 2: each wave
// aggregates 32 nodes reading indices from LDS -> X cols 128..383.
__global__ __launch_bounds__(512) void csr_agg(const int* __restrict__ be,
                                               const int* __restrict__ bt,
                                               const int* __restrict__ cnt_e,
                                               const int* __restrict__ cnt_t,
                                               const __bf16* __restrict__ entb,
                                               const __bf16* __restrict__ topb,
                                               __bf16* __restrict__ X) {
    __shared__ int lse[ECAP];       // 18.4 KB: ent cols (bucket-local CSR)
    __shared__ int lst[ECAP];       // 18.4 KB: top cols
    __shared__ int scn[256], lcur[256];
    __shared__ int nre[256], nrt[256];   // packed (start<<16)|cnt per node
    const int b = blockIdx.x;
    const int tid = threadIdx.x;
    const int base = b * ECAP;

    // ---- stream 0: ent ----
    {
        int cnt = cnt_e[b]; if (cnt > ECAP) cnt = ECAP;
        if (tid < 256) scn[tid] = 0;
        __syncthreads();
        for (int i = tid; i < cnt; i += 512)
            atomicAdd(&scn[be[base + i] >> 16], 1);
        __syncthreads();
        #pragma unroll
        for (int off = 1; off < 256; off <<= 1) {
            int v = 0;
            if (tid < 256 && tid >= off) v = scn[tid - off];
            __syncthreads();
            if (tid < 256) scn[tid] += v;
            __syncthreads();
        }
        if (tid < 256) {
            int excl = tid ? scn[tid - 1] : 0;
            nre[tid] = (excl << 16) | (scn[tid] - excl);
            lcur[tid] = excl;
        }
        __syncthreads();
        for (int i = tid; i < cnt; i += 512) {
            int v = be[base + i];
            int p = atomicAdd(&lcur[v >> 16], 1);
            lse[p] = v & 0xFFFF;
        }
    }
    __syncthreads();
    // ---- stream 1: top ----
    {
        int cnt = cnt_t[b]; if (cnt > ECAP) cnt = ECAP;
        if (tid < 256) scn[tid] = 0;
        __syncthreads();
        for (int i = tid; i < cnt; i += 512)
            atomicAdd(&scn[bt[base + i] >> 16], 1);
        __syncthreads();
        #pragma unroll
        for (int off = 1; off < 256; off <<= 1) {
            int v = 0;
            if (tid < 256 && tid >= off) v = scn[tid - off];
            __syncthreads();
            if (tid < 256) scn[tid] += v;
            __syncthreads();
        }
        if (tid < 256) {
            int excl = tid ? scn[tid - 1] : 0;
            nrt[tid] = (excl << 16) | (scn[tid] - excl);
            lcur[tid] = excl;
        }
        __syncthreads();
        for (int i = tid; i < cnt; i += 512) {
            int v = bt[base + i];
            int p = atomicAdd(&lcur[v >> 16], 1);
            lst[p] = v & 0xFFFF;
        }
    }
    __syncthreads();

    // ---- aggregate: 8 waves x 32 nodes ----
    const int wave = tid >> 6, lane = tid & 63;
    const int g = lane >> 4;        // 0..3: edge slot
    const int d = (lane & 15) * 8;  // dim group of 8
    for (int ln = wave; ln < 256; ln += 8) {
        const int node = b * 256 + ln;
        if (node >= NN) break;      // only last bucket; ln monotone -> break ok
        const int pe = nre[ln], pt = nrt[ln];
        const int e0 = pe >> 16, dege = pe & 0xFFFF;
        const int t0 = pt >> 16, degt = pt & 0xFFFF;

        float ea[8] = {0,0,0,0,0,0,0,0};
        float pa[8] = {0,0,0,0,0,0,0,0};
        const int lim = dege > degt ? dege : degt;
        for (int e = g; e < lim; e += 4) {
            if (e < dege) {
                bf16x8 v = *(const bf16x8*)(entb + (long)lse[e0 + e] * DD + d);
                #pragma unroll
                for (int j = 0; j < 8; j++) ea[j] += (float)v[j];
            }
            if (e < degt) {
                bf16x8 v = *(const bf16x8*)(topb + (long)lst[t0 + e] * DD + d);
                #pragma unroll
                for (int j = 0; j < 8; j++) pa[j] += (float)v[j];
            }
        }

        #pragma unroll
        for (int j = 0; j < 8; j++) {
            ea[j] += __shfl_xor(ea[j], 16, 64);
            ea[j] += __shfl_xor(ea[j], 32, 64);
            pa[j] += __shfl_xor(pa[j], 16, 64);
            pa[j] += __shfl_xor(pa[j], 32, 64);
        }

        const float ie = 1.0f / ((float)dege + 1e-8f);
        const float it = 1.0f / ((float)degt + 1e-8f);
        __bf16* xr = X + (long)node * K1;
        if (g == 1) {
            *(bf16x8*)(xr + DD + d) = bf16x8{f2b(ea[0]*ie), f2b(ea[1]*ie), f2b(ea[2]*ie), f2b(ea[3]*ie),
                                             f2b(ea[4]*ie), f2b(ea[5]*ie), f2b(ea[6]*ie), f2b(ea[7]*ie)};
        } else if (g == 2) {
            *(bf16x8*)(xr + 2*DD + d) = bf16x8{f2b(pa[0]*it), f2b(pa[1]*it), f2b(pa[2]*it), f2b(pa[3]*it),
                                               f2b(pa[4]*it), f2b(pa[5]*it), f2b(pa[6]*it), f2b(pa[7]*it)};
        }
    }
}

// ======== fused MLP: out = (tanh(X@W1T^T + b1)) @ W2T^T + b2 ========
// R4-measured-best structure: kt loop = 3-buffer depth-2 prefetch with
// COUNTED vmcnt + raw s_barrier; kk loop = 2-buffer __syncthreads rhythm.

// stage a [128 x 32] bf16 tile (swizzled); exactly 2 gll16 per thread
__device__ __forceinline__ void stage_tile(const __bf16* __restrict__ src, int ldK,
                                           int k0, int row0, int rowmax,
                                           __bf16* lds, int w, int lane) {
    #pragma unroll
    for (int half = 0; half < 2; half++) {
        int ss = w * 64 + half * 256 + lane;
        int r = ss >> 2;
        int sw = (r & 3) ^ ((r >> 2) & 3);
        int c = (ss & 3) ^ sw;
        int gr = row0 + r; if (gr >= rowmax) gr = rowmax - 1;
        gll16(src + (long)gr * ldK + k0 + c * 8,
              lds + (w * 64 + half * 256) * 8);
    }
}

// read fragment (logical row r, k-chunk q) from swizzled [128 x 32] tile
__device__ __forceinline__ bf16x8 frag(const __bf16* lds, int r, int q) {
    int sw = (r & 3) ^ ((r >> 2) & 3);
    return *(const bf16x8*)(lds + (r * 4 + (q ^ sw)) * 8);
}

// Hs [128 rows x 128 k] swizzled: chunk16 = kk*4+quad
__device__ __forceinline__ void hs_write(__bf16* Hs, int r, int c, __bf16 v) {
    int ch = c >> 3;
    int pch = ((((ch >> 2) ^ ((r >> 2) & 3)) << 2) | ((ch & 3) ^ (r & 3)));
    Hs[(r * 16 + pch) * 8 + (c & 7)] = v;
}
__device__ __forceinline__ bf16x8 hs_frag(const __bf16* Hs, int r, int kk, int q) {
    int pch = (((kk ^ ((r >> 2) & 3)) << 2) | (q ^ (r & 3)));
    return *(const bf16x8*)(Hs + (r * 16 + pch) * 8);
}

__global__ __launch_bounds__(256, 2) void mlp_fused(const __bf16* __restrict__ X,
                                                    const __bf16* __restrict__ W1T,
                                                    const float* __restrict__ b1,
                                                    const __bf16* __restrict__ W2T,
                                                    const float* __restrict__ b2,
                                                    float* __restrict__ out) {
    __shared__ __bf16 Xs[3][128 * 32];  // 3 x 8 KB
    __shared__ __bf16 Ws[3][128 * 32];  // 3 x 8 KB
    __shared__ __bf16 Hs[128 * 128];    // 32 KB  (total 80 KB -> 2 blocks/CU)
    const int bm = blockIdx.x * 128;
    const int t = threadIdx.x;
    const int lane = t & 63;
    const int w = t >> 6;
    const int quad = lane >> 4;
    const int l16 = lane & 15;
    const int wm = w >> 1, wn = w & 1;

    f32x4 oacc[4][4];
    #pragma unroll
    for (int i = 0; i < 4; i++)
        #pragma unroll
        for (int j = 0; j < 4; j++)
            #pragma unroll
            for (int r = 0; r < 4; r++) oacc[i][j][r] = 0.0f;

    // prologue: issue groups g0 (kt0) and g1 (kt1) for nc=0
    stage_tile(X,   K1, 0,  bm, NN,  Xs[0], w, lane);
    stage_tile(W1T, K1, 0,  0,  HID, Ws[0], w, lane);
    stage_tile(X,   K1, 32, bm, NN,  Xs[1], w, lane);
    stage_tile(W1T, K1, 32, 0,  HID, Ws[1], w, lane);

    for (int nc = 0; nc < 4; nc++) {
        f32x4 hacc[4][4];
        #pragma unroll
        for (int i = 0; i < 4; i++)
            #pragma unroll
            for (int j = 0; j < 4; j++)
                #pragma unroll
                for (int r = 0; r < 4; r++) hacc[i][j][r] = 0.0f;

        // ---- kt loop: counted-vmcnt 3-buffer pipeline ----
        #pragma unroll
        for (int kt = 0; kt < 12; kt++) {
            const int cb = kt % 3;
            // wait for this buffer's loads (issued at kt-2); keep newer group flying
            if (kt < 11) asm volatile("s_waitcnt vmcnt(4)" ::: "memory");
            else         asm volatile("s_waitcnt vmcnt(0)" ::: "memory");
            __builtin_amdgcn_s_barrier();
            bf16x8 af[4], bfr[4];
            #pragma unroll
            for (int i = 0; i < 4; i++) {
                af[i]  = frag(Xs[cb], wm * 64 + i * 16 + l16, quad);
                bfr[i] = frag(Ws[cb], wn * 64 + i * 16 + l16, quad);
            }
            if (kt < 10) {
                // stage kt+2 into buffer (kt+2)%3 (last read at kt-1; barrier-safe)
                const int nb = (kt + 2) % 3;
                stage_tile(X,   K1, (kt + 2) * 32, bm,       NN,  Xs[nb], w, lane);
                stage_tile(W1T, K1, (kt + 2) * 32, nc * 128, HID, Ws[nb], w, lane);
            }
            __builtin_amdgcn_s_setprio(1);
            #pragma unroll
            for (int i = 0; i < 4; i++)
                #pragma unroll
                for (int j = 0; j < 4; j++)
                    hacc[i][j] = __builtin_amdgcn_mfma_f32_16x16x32_bf16(af[i], bfr[j], hacc[i][j], 0, 0, 0);
            __builtin_amdgcn_s_setprio(0);
        }
        __syncthreads();   // all waves done reading Xs[2]/Ws[2]

        // stage W2 kk0 tile into Ws[2]; flies during the tanh pass
        stage_tile(W2T, HID, nc * 128, 0, OUTD, Ws[2], w, lane);

        // bias + tanh -> Hs (C/D layout: row=quad*4+reg, col=l16)
        #pragma unroll
        for (int j = 0; j < 4; j++) {
            const int col = wn * 64 + j * 16 + l16;
            const float bb = b1[nc * 128 + col];
            #pragma unroll
            for (int i = 0; i < 4; i++) {
                const int rbase = wm * 64 + i * 16 + quad * 4;
                #pragma unroll
                for (int r = 0; r < 4; r++)
                    hs_write(Hs, rbase + r, col, f2b(ftanh(hacc[i][j][r] + bb)));
            }
        }
        __syncthreads();   // Hs visible; W2 kk0 drained

        // ---- O += H_chunk @ W2T[:, nc*128..+128]^T ----
        for (int kk = 0; kk < 4; kk++) {
            __bf16* curb = (kk & 1) ? Xs[2] : Ws[2];
            __bf16* nxtb = (kk & 1) ? Ws[2] : Xs[2];
            if (kk < 3)
                stage_tile(W2T, HID, nc * 128 + (kk + 1) * 32, 0, OUTD, nxtb, w, lane);
            if (nc < 3) {
                if (kk == 2) {
                    stage_tile(X,   K1, 0, bm,             NN,  Xs[0], w, lane);
                    stage_tile(W1T, K1, 0, (nc + 1) * 128, HID, Ws[0], w, lane);
                } else if (kk == 3) {
                    stage_tile(X,   K1, 32, bm,             NN,  Xs[1], w, lane);
                    stage_tile(W1T, K1, 32, (nc + 1) * 128, HID, Ws[1], w, lane);
                }
            }
            bf16x8 af[4], bfr[4];
            #pragma unroll
            for (int i = 0; i < 4; i++) {
                af[i]  = hs_frag(Hs, wm * 64 + i * 16 + l16, kk, quad);
                bfr[i] = frag(curb, wn * 64 + i * 16 + l16, quad);
            }
            __builtin_amdgcn_s_setprio(1);
            #pragma unroll
            for (int i = 0; i < 4; i++)
                #pragma unroll
                for (int j = 0; j < 4; j++)
                    oacc[i][j] = __builtin_amdgcn_mfma_f32_16x16x32_bf16(af[i], bfr[j], oacc[i][j], 0, 0, 0);
            __builtin_amdgcn_s_setprio(0);
            __syncthreads();   // drains staged loads; separates buffer reuse
        }
    }

    // epilogue: out f32 [NN x 128]; j innermost -> full-line coverage fast
    float bb[4];
    #pragma unroll
    for (int j = 0; j < 4; j++) bb[j] = b2[wn * 64 + j * 16 + l16];
    #pragma unroll
    for (int i = 0; i < 4; i++) {
        #pragma unroll
        for (int r = 0; r < 4; r++) {
            const int gr = bm + wm * 64 + i * 16 + quad * 4 + r;
            if (gr < NN) {
                float* orow = out + (long)gr * OUTD + wn * 64 + l16;
                #pragma unroll
                for (int j = 0; j < 4; j++)
                    orow[j * 16] = oacc[i][j][r] + bb[j];
            }
        }
    }
}

extern "C" void kernel_launch(void* const* d_in, const int* in_sizes, int n_in,
                              void* d_out, int out_size, void* d_ws, size_t ws_size,
                              hipStream_t stream) {
    const float* news  = (const float*)d_in[0];
    const float* ent_f = (const float*)d_in[1];
    const float* top_f = (const float*)d_in[2];
    const int* ent_row = (const int*)d_in[3];
    const int* ent_col = (const int*)d_in[4];
    const int* top_row = (const int*)d_in[5];
    const int* top_col = (const int*)d_in[6];
    const float* W1 = (const float*)d_in[7];
    const float* b1 = (const float*)d_in[8];
    const float* W2 = (const float*)d_in[9];
    const float* b2 = (const float*)d_in[10];

    char* ws = (char*)d_ws;
    //   [1600064, 1601628)    cnt_e    int[391]
    //   [1601664, 1603228)    cnt_t    int[391]
    //   [26406336, 39206336)  entb bf16 [50000*128]
    //   [39206336, 39718336)  topb bf16 [2000*128]
    //   [40000000, 47206912)  be packed int[391*4608]
    //   [48000000, 55206912)  bt packed int[391*4608]
    //   [102400000,179200000) X bf16 [100000*384]
    //   [179200000,179593216) W1T bf16 [512*384]
    //   [179593216,179724288) W2T bf16 [128*512]
    int* cnt_e    = (int*)(ws + 1600064);
    int* cnt_t    = (int*)(ws + 1601664);
    __bf16* entb = (__bf16*)(ws + 26406336);
    __bf16* topb = (__bf16*)(ws + 39206336);
    int* be      = (int*)(ws + 40000000);
    int* bt      = (int*)(ws + 48000000);
    __bf16* X   = (__bf16*)(ws + 102400000);
    __bf16* W1T = (__bf16*)(ws + 179200000);
    __bf16* W2T = (__bf16*)(ws + 179593216);

    hipMemsetAsync(ws + 1600064, 0, 3200, stream);   // zero cnt_e/cnt_t
    prep<<<CFB + SCB + CWB, 256, 0, stream>>>(ent_f, top_f, news,
                                              ent_row, ent_col, top_row, top_col,
                                              W1, W2, entb, topb, X,
                                              cnt_e, cnt_t, be, bt, W1T, W2T);
    csr_agg<<<NBKT, 512, 0, stream>>>(be, bt, cnt_e, cnt_t, entb, topb, X);
    mlp_fused<<<782, 256, 0, stream>>>(X, W1T, b1, W2T, b2, (float*)d_out);
}

// Round 17
// 556.459 us; speedup vs baseline: 1.0436x; 1.0436x over previous
//
#include <hip/hip_runtime.h>
#include <hip/hip_bf16.h>

#define NN 100000
#define NE 50000
#define NT 2000
#define DD 128
#define NEDGE 1600000
#define HID 512
#define OUTD 128
#define K1 (3*DD)   // 384: X layout [news | ent_agg | top_agg]
#define NBKT 391    // ceil(100000/256) buckets of 256 nodes
#define ECAP 4608   // fixed bucket capacity: mean 4096 + 8 sigma

typedef __bf16 bf16x8 __attribute__((ext_vector_type(8)));
typedef __bf16 bf16x4 __attribute__((ext_vector_type(4)));
typedef float  f32x4  __attribute__((ext_vector_type(4)));

__device__ __forceinline__ __bf16 f2b(float f) {
    __hip_bfloat16 h = __float2bfloat16(f);
    union { __hip_bfloat16 h; __bf16 b; } u; u.h = h; return u.b;
}

__device__ __forceinline__ void gll16(const void* g, void* l) {
    __builtin_amdgcn_global_load_lds((const __attribute__((address_space(1))) void*)g,
                                     (__attribute__((address_space(3))) void*)l, 16, 0, 0);
}

__device__ __forceinline__ float ftanh(float x) {
    x = fminf(fmaxf(x, -15.f), 15.f);
    float t = __expf(2.f * x);
    return (t - 1.f) / (t + 1.f);
}

// ---- convert: ent/top tables -> bf16 tables; news -> bf16 into X cols 0..127 ----
__global__ void conv_feats(const float* __restrict__ entf, const float* __restrict__ topf,
                           const float* __restrict__ news,
                           __bf16* __restrict__ entb, __bf16* __restrict__ topb,
                           __bf16* __restrict__ X) {
    long i = ((long)blockIdx.x * 256 + threadIdx.x) * 4;
    const long NEL = (long)NE * DD;            // 6.4M
    const long NTL = (long)NT * DD;            // 0.256M
    if (i < NEL) {
        float4 v = *(const float4*)(entf + i);
        *(bf16x4*)(entb + i) = bf16x4{f2b(v.x), f2b(v.y), f2b(v.z), f2b(v.w)};
    } else if (i < NEL + NTL) {
        long j = i - NEL;
        float4 v = *(const float4*)(topf + j);
        *(bf16x4*)(topb + j) = bf16x4{f2b(v.x), f2b(v.y), f2b(v.z), f2b(v.w)};
    } else {
        long j = i - NEL - NTL;                // 0 .. 12.8M
        long row = j >> 7, col = j & 127;      // news [NN x 128], 4-aligned col
        float4 v = *(const float4*)(news + j);
        *(bf16x4*)(X + row * K1 + col) = bf16x4{f2b(v.x), f2b(v.y), f2b(v.z), f2b(v.w)};
    }
}

// ---- partition edges into fixed-capacity buckets ----
// 16384 edges/block: per-block bucket runs ~42 edges (~168 B) -> write
// amplification ~1.3x instead of ~2.7x at 4096/block (R16 prep counters:
// WRITE_SIZE 106 MB vs 52 logical was the scatter's 4B-random-write RMW cost).
__global__ __launch_bounds__(256) void scatter_bucket(const int* __restrict__ er,
                                                      const int* __restrict__ ec,
                                                      const int* __restrict__ tr,
                                                      const int* __restrict__ tc,
                                                      int* __restrict__ cnt_e,
                                                      int* __restrict__ cnt_t,
                                                      int* __restrict__ be,
                                                      int* __restrict__ bt) {
    __shared__ int lhe[NBKT], lht[NBKT];   // counts, then local cursors
    __shared__ int lbe[NBKT], lbt[NBKT];   // reserved global bases
    const int tid = threadIdx.x;
    for (int i = tid; i < NBKT; i += 256) { lhe[i] = 0; lht[i] = 0; }
    __syncthreads();
    const int base = blockIdx.x * 16384;
    #pragma unroll 4
    for (int k = 0; k < 64; k++) {
        int e = base + k * 256 + tid;
        if (e < NEDGE) {
            atomicAdd(&lhe[er[e] >> 8], 1);
            atomicAdd(&lht[tr[e] >> 8], 1);
        }
    }
    __syncthreads();
    for (int i = tid; i < NBKT; i += 256) {
        int c = lhe[i];
        lbe[i] = c ? (i * ECAP + atomicAdd(&cnt_e[i], c)) : 0;
        lhe[i] = 0;
        c = lht[i];
        lbt[i] = c ? (i * ECAP + atomicAdd(&cnt_t[i], c)) : 0;
        lht[i] = 0;
    }
    __syncthreads();
    #pragma unroll 4
    for (int k = 0; k < 64; k++) {
        int e = base + k * 256 + tid;
        if (e < NEDGE) {
            int r = er[e];
            int b = r >> 8;
            int p = lbe[b] + atomicAdd(&lhe[b], 1);
            be[p] = ((r & 255) << 16) | ec[e];
            r = tr[e];
            b = r >> 8;
            p = lbt[b] + atomicAdd(&lht[b], 1);
            bt[p] = ((r & 255) << 16) | tc[e];
        }
    }
}

// ---- per-bucket exact CSR: local hist + scan -> per-node [starts,ends) + cols ----
__global__ __launch_bounds__(256) void bucket_csr(const int* __restrict__ be,
                                                  const int* __restrict__ bt,
                                                  const int* __restrict__ cnt_e,
                                                  const int* __restrict__ cnt_t,
                                                  int* __restrict__ starts_e,
                                                  int* __restrict__ ends_e,
                                                  int* __restrict__ starts_t,
                                                  int* __restrict__ ends_t,
                                                  int* __restrict__ se,
                                                  int* __restrict__ st) {
    const int* buf  = blockIdx.y ? bt : be;
    const int* bcnt = blockIdx.y ? cnt_t : cnt_e;
    int* starts     = blockIdx.y ? starts_t : starts_e;
    int* ends       = blockIdx.y ? ends_t : ends_e;
    int* sout       = blockIdx.y ? st : se;
    const int b = blockIdx.x;
    const int tid = threadIdx.x;
    const int start = b * ECAP;
    int cnt = bcnt[b]; if (cnt > ECAP) cnt = ECAP;   // safety clamp

    __shared__ int scn[256];
    __shared__ int lcur[256];
    scn[tid] = 0;
    __syncthreads();
    for (int i = tid; i < cnt; i += 256)
        atomicAdd(&scn[buf[start + i] >> 16], 1);
    __syncthreads();
    #pragma unroll
    for (int off = 1; off < 256; off <<= 1) {
        int v = (tid >= off) ? scn[tid - off] : 0;
        __syncthreads();
        scn[tid] += v;
        __syncthreads();
    }
    const int node = b * 256 + tid;
    const int excl = start + (tid ? scn[tid - 1] : 0);
    if (node < NN) {
        starts[node] = excl;
        ends[node]   = start + scn[tid];
    }
    lcur[tid] = excl;
    __syncthreads();
    for (int i = tid; i < cnt; i += 256) {
        int v = buf[start + i];
        int p = atomicAdd(&lcur[v >> 16], 1);
        sout[p] = v & 0xFFFF;
    }
}

// ---- gather-aggregate (bf16 tables) -> X cols 128..383 ----
// One wave per node; coalesced index loads staged to per-wave LDS slab.
__global__ __launch_bounds__(256) void aggregate2(const __bf16* __restrict__ entb,
                                                  const __bf16* __restrict__ topb,
                                                  const int* __restrict__ starts_e,
                                                  const int* __restrict__ ends_e,
                                                  const int* __restrict__ starts_t,
                                                  const int* __restrict__ ends_t,
                                                  const int* __restrict__ se,
                                                  const int* __restrict__ st,
                                                  __bf16* __restrict__ X) {
    __shared__ int sidx[4][128];   // [wave][0..63 ent, 64..127 top]
    const int wave = threadIdx.x >> 6, lane = threadIdx.x & 63;
    const int node = blockIdx.x * 4 + wave;
    if (node >= NN) return;
    const int g = lane >> 4;        // 0..3: edge slot
    const int d = (lane & 15) * 8;  // dim group of 8

    const int s0 = starts_e[node], s1 = ends_e[node];
    const int t0 = starts_t[node], t1 = ends_t[node];
    const int dege = s1 - s0, degt = t1 - t0;
    const int lim_e = dege < 64 ? dege : 64;
    const int lim_t = degt < 64 ? degt : 64;

    int* my = sidx[wave];
    if (lane < lim_e) my[lane] = se[s0 + lane];
    if (lane < lim_t) my[64 + lane] = st[t0 + lane];

    float ea[8] = {0,0,0,0,0,0,0,0};
    float pa[8] = {0,0,0,0,0,0,0,0};

    const int lim = lim_e > lim_t ? lim_e : lim_t;
    for (int e = g; e < lim; e += 4) {
        if (e < lim_e) {
            bf16x8 v = *(const bf16x8*)(entb + (long)my[e] * DD + d);
            #pragma unroll
            for (int j = 0; j < 8; j++) ea[j] += (float)v[j];
        }
        if (e < lim_t) {
            bf16x8 v = *(const bf16x8*)(topb + (long)my[64 + e] * DD + d);
            #pragma unroll
            for (int j = 0; j < 8; j++) pa[j] += (float)v[j];
        }
    }
    // cold tails (deg>64: P ~ 1e-7)
    for (int e = 64 + g; e < dege; e += 4) {
        bf16x8 v = *(const bf16x8*)(entb + (long)se[s0 + e] * DD + d);
        #pragma unroll
        for (int j = 0; j < 8; j++) ea[j] += (float)v[j];
    }
    for (int e = 64 + g; e < degt; e += 4) {
        bf16x8 v = *(const bf16x8*)(topb + (long)st[t0 + e] * DD + d);
        #pragma unroll
        for (int j = 0; j < 8; j++) pa[j] += (float)v[j];
    }

    #pragma unroll
    for (int j = 0; j < 8; j++) {
        ea[j] += __shfl_xor(ea[j], 16, 64);
        ea[j] += __shfl_xor(ea[j], 32, 64);
        pa[j] += __shfl_xor(pa[j], 16, 64);
        pa[j] += __shfl_xor(pa[j], 32, 64);
    }

    const float ie = 1.0f / ((float)dege + 1e-8f);
    const float it = 1.0f / ((float)degt + 1e-8f);
    __bf16* xr = X + (long)node * K1;
    if (g == 1) {
        *(bf16x8*)(xr + DD + d) = bf16x8{f2b(ea[0]*ie), f2b(ea[1]*ie), f2b(ea[2]*ie), f2b(ea[3]*ie),
                                         f2b(ea[4]*ie), f2b(ea[5]*ie), f2b(ea[6]*ie), f2b(ea[7]*ie)};
    } else if (g == 2) {
        *(bf16x8*)(xr + 2*DD + d) = bf16x8{f2b(pa[0]*it), f2b(pa[1]*it), f2b(pa[2]*it), f2b(pa[3]*it),
                                           f2b(pa[4]*it), f2b(pa[5]*it), f2b(pa[6]*it), f2b(pa[7]*it)};
    }
}

// ---- W1 [384,512] -> W1T bf16 [512,384]; W2 [512,128] -> W2T bf16 [128,512] ----
__global__ void conv_w(const float* __restrict__ W1, const float* __restrict__ W2,
                       __bf16* __restrict__ W1T, __bf16* __restrict__ W2T) {
    int i = blockIdx.x * 256 + threadIdx.x;
    if (i < K1 * HID) {
        int k = i / HID, n = i % HID;
        W1T[n * K1 + k] = f2b(W1[i]);
    } else {
        int j = i - K1 * HID;
        if (j < HID * OUTD) {
            int k = j / OUTD, n = j % OUTD;
            W2T[n * HID + k] = f2b(W2[j]);
        }
    }
}

// ======== fused MLP: out = (tanh(X@W1T^T + b1)) @ W2T^T + b2 ========
// R4-measured-best structure: kt loop = 3-buffer depth-2 prefetch with
// COUNTED vmcnt + raw s_barrier; kk loop = 2-buffer __syncthreads rhythm.

// stage a [128 x 32] bf16 tile (swizzled); exactly 2 gll16 per thread
__device__ __forceinline__ void stage_tile(const __bf16* __restrict__ src, int ldK,
                                           int k0, int row0, int rowmax,
                                           __bf16* lds, int w, int lane) {
    #pragma unroll
    for (int half = 0; half < 2; half++) {
        int ss = w * 64 + half * 256 + lane;
        int r = ss >> 2;
        int sw = (r & 3) ^ ((r >> 2) & 3);
        int c = (ss & 3) ^ sw;
        int gr = row0 + r; if (gr >= rowmax) gr = rowmax - 1;
        gll16(src + (long)gr * ldK + k0 + c * 8,
              lds + (w * 64 + half * 256) * 8);
    }
}

// read fragment (logical row r, k-chunk q) from swizzled [128 x 32] tile
__device__ __forceinline__ bf16x8 frag(const __bf16* lds, int r, int q) {
    int sw = (r & 3) ^ ((r >> 2) & 3);
    return *(const bf16x8*)(lds + (r * 4 + (q ^ sw)) * 8);
}

// Hs [128 rows x 128 k] swizzled: chunk16 = kk*4+quad
__device__ __forceinline__ void hs_write(__bf16* Hs, int r, int c, __bf16 v) {
    int ch = c >> 3;
    int pch = ((((ch >> 2) ^ ((r >> 2) & 3)) << 2) | ((ch & 3) ^ (r & 3)));
    Hs[(r * 16 + pch) * 8 + (c & 7)] = v;
}
__device__ __forceinline__ bf16x8 hs_frag(const __bf16* Hs, int r, int kk, int q) {
    int pch = (((kk ^ ((r >> 2) & 3)) << 2) | (q ^ (r & 3)));
    return *(const bf16x8*)(Hs + (r * 16 + pch) * 8);
}

__global__ __launch_bounds__(256, 2) void mlp_fused(const __bf16* __restrict__ X,
                                                    const __bf16* __restrict__ W1T,
                                                    const float* __restrict__ b1,
                                                    const __bf16* __restrict__ W2T,
                                                    const float* __restrict__ b2,
                                                    float* __restrict__ out) {
    __shared__ __bf16 Xs[3][128 * 32];  // 3 x 8 KB
    __shared__ __bf16 Ws[3][128 * 32];  // 3 x 8 KB
    __shared__ __bf16 Hs[128 * 128];    // 32 KB  (total 80 KB -> 2 blocks/CU)
    const int bm = blockIdx.x * 128;
    const int t = threadIdx.x;
    const int lane = t & 63;
    const int w = t >> 6;
    const int quad = lane >> 4;
    const int l16 = lane & 15;
    const int wm = w >> 1, wn = w & 1;

    f32x4 oacc[4][4];
    #pragma unroll
    for (int i = 0; i < 4; i++)
        #pragma unroll
        for (int j = 0; j < 4; j++)
            #pragma unroll
            for (int r = 0; r < 4; r++) oacc[i][j][r] = 0.0f;

    // prologue: issue groups g0 (kt0) and g1 (kt1) for nc=0
    stage_tile(X,   K1, 0,  bm, NN,  Xs[0], w, lane);
    stage_tile(W1T, K1, 0,  0,  HID, Ws[0], w, lane);
    stage_tile(X,   K1, 32, bm, NN,  Xs[1], w, lane);
    stage_tile(W1T, K1, 32, 0,  HID, Ws[1], w, lane);

    for (int nc = 0; nc < 4; nc++) {
        f32x4 hacc[4][4];
        #pragma unroll
        for (int i = 0; i < 4; i++)
            #pragma unroll
            for (int j = 0; j < 4; j++)
                #pragma unroll
                for (int r = 0; r < 4; r++) hacc[i][j][r] = 0.0f;

        // ---- kt loop: counted-vmcnt 3-buffer pipeline ----
        #pragma unroll
        for (int kt = 0; kt < 12; kt++) {
            const int cb = kt % 3;
            // wait for this buffer's loads (issued at kt-2); keep newer group flying
            if (kt < 11) asm volatile("s_waitcnt vmcnt(4)" ::: "memory");
            else         asm volatile("s_waitcnt vmcnt(0)" ::: "memory");
            __builtin_amdgcn_s_barrier();
            bf16x8 af[4], bfr[4];
            #pragma unroll
            for (int i = 0; i < 4; i++) {
                af[i]  = frag(Xs[cb], wm * 64 + i * 16 + l16, quad);
                bfr[i] = frag(Ws[cb], wn * 64 + i * 16 + l16, quad);
            }
            if (kt < 10) {
                // stage kt+2 into buffer (kt+2)%3 (last read at kt-1; barrier-safe)
                const int nb = (kt + 2) % 3;
                stage_tile(X,   K1, (kt + 2) * 32, bm,       NN,  Xs[nb], w, lane);
                stage_tile(W1T, K1, (kt + 2) * 32, nc * 128, HID, Ws[nb], w, lane);
            }
            __builtin_amdgcn_s_setprio(1);
            #pragma unroll
            for (int i = 0; i < 4; i++)
                #pragma unroll
                for (int j = 0; j < 4; j++)
                    hacc[i][j] = __builtin_amdgcn_mfma_f32_16x16x32_bf16(af[i], bfr[j], hacc[i][j], 0, 0, 0);
            __builtin_amdgcn_s_setprio(0);
        }
        __syncthreads();   // all waves done reading Xs[2]/Ws[2]

        // stage W2 kk0 tile into Ws[2]; flies during the tanh pass
        stage_tile(W2T, HID, nc * 128, 0, OUTD, Ws[2], w, lane);

        // bias + tanh -> Hs (C/D layout: row=quad*4+reg, col=l16)
        #pragma unroll
        for (int j = 0; j < 4; j++) {
            const int col = wn * 64 + j * 16 + l16;
            const float bb = b1[nc * 128 + col];
            #pragma unroll
            for (int i = 0; i < 4; i++) {
                const int rbase = wm * 64 + i * 16 + quad * 4;
                #pragma unroll
                for (int r = 0; r < 4; r++)
                    hs_write(Hs, rbase + r, col, f2b(ftanh(hacc[i][j][r] + bb)));
            }
        }
        __syncthreads();   // Hs visible; W2 kk0 drained

        // ---- O += H_chunk @ W2T[:, nc*128..+128]^T ----
        for (int kk = 0; kk < 4; kk++) {
            __bf16* curb = (kk & 1) ? Xs[2] : Ws[2];
            __bf16* nxtb = (kk & 1) ? Ws[2] : Xs[2];
            if (kk < 3)
                stage_tile(W2T, HID, nc * 128 + (kk + 1) * 32, 0, OUTD, nxtb, w, lane);
            if (nc < 3) {
                if (kk == 2) {
                    stage_tile(X,   K1, 0, bm,             NN,  Xs[0], w, lane);
                    stage_tile(W1T, K1, 0, (nc + 1) * 128, HID, Ws[0], w, lane);
                } else if (kk == 3) {
                    stage_tile(X,   K1, 32, bm,             NN,  Xs[1], w, lane);
                    stage_tile(W1T, K1, 32, (nc + 1) * 128, HID, Ws[1], w, lane);
                }
            }
            bf16x8 af[4], bfr[4];
            #pragma unroll
            for (int i = 0; i < 4; i++) {
                af[i]  = hs_frag(Hs, wm * 64 + i * 16 + l16, kk, quad);
                bfr[i] = frag(curb, wn * 64 + i * 16 + l16, quad);
            }
            __builtin_amdgcn_s_setprio(1);
            #pragma unroll
            for (int i = 0; i < 4; i++)
                #pragma unroll
                for (int j = 0; j < 4; j++)
                    oacc[i][j] = __builtin_amdgcn_mfma_f32_16x16x32_bf16(af[i], bfr[j], oacc[i][j], 0, 0, 0);
            __builtin_amdgcn_s_setprio(0);
            __syncthreads();   // drains staged loads; separates buffer reuse
        }
    }

    // epilogue: out f32 [NN x 128]; j innermost -> full-line coverage fast
    float bb[4];
    #pragma unroll
    for (int j = 0; j < 4; j++) bb[j] = b2[wn * 64 + j * 16 + l16];
    #pragma unroll
    for (int i = 0; i < 4; i++) {
        #pragma unroll
        for (int r = 0; r < 4; r++) {
            const int gr = bm + wm * 64 + i * 16 + quad * 4 + r;
            if (gr < NN) {
                float* orow = out + (long)gr * OUTD + wn * 64 + l16;
                #pragma unroll
                for (int j = 0; j < 4; j++)
                    orow[j * 16] = oacc[i][j][r] + bb[j];
            }
        }
    }
}

extern "C" void kernel_launch(void* const* d_in, const int* in_sizes, int n_in,
                              void* d_out, int out_size, void* d_ws, size_t ws_size,
                              hipStream_t stream) {
    const float* news  = (const float*)d_in[0];
    const float* ent_f = (const float*)d_in[1];
    const float* top_f = (const float*)d_in[2];
    const int* ent_row = (const int*)d_in[3];
    const int* ent_col = (const int*)d_in[4];
    const int* top_row = (const int*)d_in[5];
    const int* top_col = (const int*)d_in[6];
    const float* W1 = (const float*)d_in[7];
    const float* b1 = (const float*)d_in[8];
    const float* W2 = (const float*)d_in[9];
    const float* b2 = (const float*)d_in[10];

    char* ws = (char*)d_ws;
    //   [0,        400000)    starts_e int[100000]
    //   [400016,   800016)    ends_e   int[100000]
    //   [800032,  1200032)    starts_t int[100000]
    //   [1200048, 1600048)    ends_t   int[100000]
    //   [1600064, 1601628)    cnt_e    int[391]
    //   [1601664, 1603228)    cnt_t    int[391]
    //   [26406336, 39206336)  entb bf16 [50000*128]
    //   [39206336, 39718336)  topb bf16 [2000*128]
    //   [40000000, 47206912)  be packed int[391*4608]
    //   [48000000, 55206912)  bt packed int[391*4608]
    //   [56000000, 63206912)  se int[391*4608]
    //   [64000000, 71206912)  st int[391*4608]
    //   [102400000,179200000) X bf16 [100000*384]
    //   [179200000,179593216) W1T bf16 [512*384]
    //   [179593216,179724288) W2T bf16 [128*512]
    int* starts_e = (int*)(ws + 0);
    int* ends_e   = (int*)(ws + 400016);
    int* starts_t = (int*)(ws + 800032);
    int* ends_t   = (int*)(ws + 1200048);
    int* cnt_e    = (int*)(ws + 1600064);
    int* cnt_t    = (int*)(ws + 1601664);
    __bf16* entb = (__bf16*)(ws + 26406336);
    __bf16* topb = (__bf16*)(ws + 39206336);
    int* be      = (int*)(ws + 40000000);
    int* bt      = (int*)(ws + 48000000);
    int* se      = (int*)(ws + 56000000);
    int* st      = (int*)(ws + 64000000);
    __bf16* X   = (__bf16*)(ws + 102400000);
    __bf16* W1T = (__bf16*)(ws + 179200000);
    __bf16* W2T = (__bf16*)(ws + 179593216);

    hipMemsetAsync(ws + 1600064, 0, 3200, stream);   // zero cnt_e/cnt_t
    conv_w<<<1024, 256, 0, stream>>>(W1, W2, W1T, W2T);
    conv_feats<<<19000, 256, 0, stream>>>(ent_f, top_f, news, entb, topb, X);
    scatter_bucket<<<98, 256, 0, stream>>>(ent_row, ent_col, top_row, top_col,
                                           cnt_e, cnt_t, be, bt);
    bucket_csr<<<dim3(NBKT, 2), 256, 0, stream>>>(be, bt, cnt_e, cnt_t,
                                                  starts_e, ends_e, starts_t, ends_t,
                                                  se, st);
    aggregate2<<<NN / 4, 256, 0, stream>>>(entb, topb, starts_e, ends_e,
                                           starts_t, ends_t, se, st, X);
    mlp_fused<<<782, 256, 0, stream>>>(X, W1T, b1, W2T, b2, (float*)d_out);
}